// Round 1
// baseline (258.136 us; speedup 1.0000x reference)
//
#include <hip/hip_runtime.h>
#include <hip/hip_bf16.h>

typedef __bf16 bf16;
typedef bf16 bf16x8 __attribute__((ext_vector_type(8)));
typedef bf16 bf16x4v __attribute__((ext_vector_type(4)));
typedef float f32x4 __attribute__((ext_vector_type(4)));

#define LN_EPS 1e-5f

// ---------------- LayerNorm rows: f32 [R][256] -> bf16 [R][256] ----------------
__global__ __launch_bounds__(256) void ln_rows_kernel(
    const float* __restrict__ in, const float* __restrict__ w,
    const float* __restrict__ b, bf16* __restrict__ out)
{
  int row = blockIdx.x * 4 + (threadIdx.x >> 6);
  int lane = threadIdx.x & 63;
  const float4* p = (const float4*)(in + (size_t)row * 256);
  float4 v = p[lane];
  float s = v.x + v.y + v.z + v.w;
  float q = v.x*v.x + v.y*v.y + v.z*v.z + v.w*v.w;
  #pragma unroll
  for (int o = 32; o; o >>= 1) { s += __shfl_xor(s, o); q += __shfl_xor(q, o); }
  float mu = s * (1.0f/256.0f);
  float rs = rsqrtf(q*(1.0f/256.0f) - mu*mu + LN_EPS);
  float4 wv = ((const float4*)w)[lane];
  float4 bv = ((const float4*)b)[lane];
  bf16x4v o4;
  o4[0] = (bf16)((v.x - mu)*rs*wv.x + bv.x);
  o4[1] = (bf16)((v.y - mu)*rs*wv.y + bv.y);
  o4[2] = (bf16)((v.z - mu)*rs*wv.z + bv.z);
  o4[3] = (bf16)((v.w - mu)*rs*wv.w + bv.w);
  *(bf16x4v*)(out + (size_t)row * 256 + lane * 4) = o4;
}

// ---------------- transpose f32 [R][C] -> bf16 [C][R] (weights) ----------------
__global__ __launch_bounds__(256) void transpose_f32_bf16(
    const float* __restrict__ in, bf16* __restrict__ out, int R, int C)
{
  __shared__ float tile[32][33];
  int bc = blockIdx.x * 32, br = blockIdx.y * 32;
  int tx = threadIdx.x, ty = threadIdx.y;
  #pragma unroll
  for (int i = ty; i < 32; i += 8)
    tile[i][tx] = in[(size_t)(br + i) * C + bc + tx];
  __syncthreads();
  #pragma unroll
  for (int i = ty; i < 32; i += 8)
    out[(size_t)(bc + i) * R + br + tx] = (bf16)tile[tx][i];
}

// ------- symmetrize + LN + WA: rr [512,512,256] -> S [i][j][4] f32 (symmetric) -------
// Each (i,j) pair with tile(ti<=tj) is computed once; rr read exactly once (268 MB).
__global__ __launch_bounds__(256) void sym_ln_wa_kernel(
    const float* __restrict__ rr, const float* __restrict__ w,
    const float* __restrict__ b, const float* __restrict__ WA,
    float* __restrict__ S)
{
  int rem = blockIdx.x; int ti = 0; int len = 32;
  while (rem >= len) { rem -= len; ti++; len--; }
  int tj = ti + rem;
  int wid = threadIdx.x >> 6, lane = threadIdx.x & 63;
  int c0 = lane * 4;
  float4 wv = ((const float4*)w)[lane];
  float4 bv = ((const float4*)b)[lane];
  const float4* wa4 = (const float4*)WA;   // WA[c][g], rows of 4 g
  float4 wa0 = wa4[c0+0], wa1 = wa4[c0+1], wa2 = wa4[c0+2], wa3 = wa4[c0+3];
  int pend = blockIdx.y * 128 + 128;
  for (int p = blockIdx.y * 128 + wid; p < pend; p += 4) {
    int i = ti*16 + (p >> 4), j = tj*16 + (p & 15);
    float4 a = ((const float4*)(rr + ((size_t)i*512 + j)*256))[lane];
    float4 c = ((const float4*)(rr + ((size_t)j*512 + i)*256))[lane];
    float ex = 0.5f*(a.x + c.x), ey = 0.5f*(a.y + c.y),
          ez = 0.5f*(a.z + c.z), ew = 0.5f*(a.w + c.w);
    float s = ex+ey+ez+ew;
    float q = ex*ex+ey*ey+ez*ez+ew*ew;
    #pragma unroll
    for (int o = 32; o; o >>= 1) { s += __shfl_xor(s, o); q += __shfl_xor(q, o); }
    float mu = s*(1.f/256.f);
    float rs = rsqrtf(q*(1.f/256.f) - mu*mu + LN_EPS);
    float nx = (ex-mu)*rs*wv.x + bv.x;
    float ny = (ey-mu)*rs*wv.y + bv.y;
    float nz = (ez-mu)*rs*wv.z + bv.z;
    float nw = (ew-mu)*rs*wv.w + bv.w;
    float g0 = nx*wa0.x + ny*wa1.x + nz*wa2.x + nw*wa3.x;
    float g1 = nx*wa0.y + ny*wa1.y + nz*wa2.y + nw*wa3.y;
    float g2 = nx*wa0.z + ny*wa1.z + nz*wa2.z + nw*wa3.z;
    float g3 = nx*wa0.w + ny*wa1.w + nz*wa2.w + nw*wa3.w;
    #pragma unroll
    for (int o = 32; o; o >>= 1) {
      g0 += __shfl_xor(g0, o); g1 += __shfl_xor(g1, o);
      g2 += __shfl_xor(g2, o); g3 += __shfl_xor(g3, o);
    }
    if (lane == 0) {
      float4 r4 = make_float4(g0, g1, g2, g3);  // bA omitted: cancels in softmax
      ((float4*)S)[(size_t)i*512 + j] = r4;
      ((float4*)S)[(size_t)j*512 + i] = r4;
    }
  }
}

// ---------------- softmax over j: S [i][j][4] f32 -> A bf16 [g][i][j] ----------------
__global__ __launch_bounds__(256) void softmax_kernel(
    const float* __restrict__ S, bf16* __restrict__ Aout)
{
  int i = blockIdx.x * 4 + (threadIdx.x >> 6);
  int lane = threadIdx.x & 63;
  const float4* Sr = (const float4*)S + (size_t)i * 512;
  float4 s[8];
  float m0 = -1e30f, m1 = -1e30f, m2 = -1e30f, m3 = -1e30f;
  #pragma unroll
  for (int it = 0; it < 8; it++) {
    s[it] = Sr[lane + it*64];
    m0 = fmaxf(m0, s[it].x); m1 = fmaxf(m1, s[it].y);
    m2 = fmaxf(m2, s[it].z); m3 = fmaxf(m3, s[it].w);
  }
  #pragma unroll
  for (int o = 32; o; o >>= 1) {
    m0 = fmaxf(m0, __shfl_xor(m0, o)); m1 = fmaxf(m1, __shfl_xor(m1, o));
    m2 = fmaxf(m2, __shfl_xor(m2, o)); m3 = fmaxf(m3, __shfl_xor(m3, o));
  }
  float t0=0.f, t1=0.f, t2=0.f, t3=0.f;
  #pragma unroll
  for (int it = 0; it < 8; it++) {
    s[it].x = __expf(s[it].x - m0); t0 += s[it].x;
    s[it].y = __expf(s[it].y - m1); t1 += s[it].y;
    s[it].z = __expf(s[it].z - m2); t2 += s[it].z;
    s[it].w = __expf(s[it].w - m3); t3 += s[it].w;
  }
  #pragma unroll
  for (int o = 32; o; o >>= 1) {
    t0 += __shfl_xor(t0, o); t1 += __shfl_xor(t1, o);
    t2 += __shfl_xor(t2, o); t3 += __shfl_xor(t3, o);
  }
  t0 = 1.f/t0; t1 = 1.f/t1; t2 = 1.f/t2; t3 = 1.f/t3;
  bf16* A0 = Aout + (size_t)i * 512;
  #pragma unroll
  for (int it = 0; it < 8; it++) {
    int j = lane + it*64;
    A0[j]          = (bf16)(s[it].x * t0);
    A0[262144 + j] = (bf16)(s[it].y * t1);
    A0[524288 + j] = (bf16)(s[it].z * t2);
    A0[786432 + j] = (bf16)(s[it].w * t3);
  }
}

// ---------------- generic MFMA GEMM: C[M,N] = A[M,K] @ Bt[N,K]^T ----------------
// MODE 0: Vt epilogue (bias per row=c, scatter to Vt[g][d*64+c6][j])
// MODE 1: agg epilogue (per-g, scatter to agg[(d*512+i)][g*64+c6])
// MODE 2: +bias[n] +resid, write f32
// MODE 3: relu(+bias[n]), write bf16
template<int MODE>
__global__ __launch_bounds__(256) void gemm_bt_kernel(
    const bf16* __restrict__ Aglob, const bf16* __restrict__ Bglob,
    void* __restrict__ outP, const float* __restrict__ bias,
    const float* __restrict__ resid, int M, int N, int K)
{
  __shared__ bf16 As[128][40];
  __shared__ bf16 Bs[128][40];
  int g = blockIdx.z;
  const bf16* Ag = Aglob;
  const bf16* Bg = Bglob;
  if (MODE == 1) { Ag += (size_t)g * 512 * 512; Bg += (size_t)g * 4096 * 512; }
  int bm = blockIdx.y * 128, bn = blockIdx.x * 128;
  int tid = threadIdx.x;
  int wid = tid >> 6, lane = tid & 63;
  int wm = (wid >> 1) * 64, wn = (wid & 1) * 64;
  f32x4 acc[4][4];
  #pragma unroll
  for (int mi = 0; mi < 4; mi++)
    #pragma unroll
    for (int ni = 0; ni < 4; ni++)
      acc[mi][ni] = (f32x4){0.f, 0.f, 0.f, 0.f};
  int r0 = tid >> 2;
  int koff = (tid & 3) * 8;
  int fr = lane & 15, fk = (lane >> 4) * 8;
  for (int k0 = 0; k0 < K; k0 += 32) {
    __syncthreads();
    *(bf16x8*)&As[r0][koff]    = *(const bf16x8*)&Ag[(size_t)(bm + r0) * K + k0 + koff];
    *(bf16x8*)&As[r0+64][koff] = *(const bf16x8*)&Ag[(size_t)(bm + r0 + 64) * K + k0 + koff];
    *(bf16x8*)&Bs[r0][koff]    = *(const bf16x8*)&Bg[(size_t)(bn + r0) * K + k0 + koff];
    *(bf16x8*)&Bs[r0+64][koff] = *(const bf16x8*)&Bg[(size_t)(bn + r0 + 64) * K + k0 + koff];
    __syncthreads();
    bf16x8 af[4], bf_[4];
    #pragma unroll
    for (int mi = 0; mi < 4; mi++) af[mi] = *(const bf16x8*)&As[wm + mi*16 + fr][fk];
    #pragma unroll
    for (int ni = 0; ni < 4; ni++) bf_[ni] = *(const bf16x8*)&Bs[wn + ni*16 + fr][fk];
    #pragma unroll
    for (int mi = 0; mi < 4; mi++)
      #pragma unroll
      for (int ni = 0; ni < 4; ni++)
        acc[mi][ni] = __builtin_amdgcn_mfma_f32_16x16x32_bf16(af[mi], bf_[ni], acc[mi][ni], 0, 0, 0);
  }
  int cn0 = lane & 15;
  int rq = (lane >> 4) * 4;
  #pragma unroll
  for (int mi = 0; mi < 4; mi++) {
    #pragma unroll
    for (int ni = 0; ni < 4; ni++) {
      int mb = bm + wm + mi*16 + rq;
      int nc = bn + wn + ni*16 + cn0;
      #pragma unroll
      for (int r = 0; r < 4; r++) {
        int mr = mb + r;
        float v = acc[mi][ni][r];
        if (MODE == 0) {
          v += bias[mr];
          int gg = mr >> 6, rp = mr & 63, d = nc >> 9, j = nc & 511;
          ((bf16*)outP)[((size_t)gg*4096 + d*64 + rp)*512 + j] = (bf16)v;
        } else if (MODE == 1) {
          int d = nc >> 6, c6 = nc & 63;
          ((bf16*)outP)[((size_t)d*512 + mr)*256 + g*64 + c6] = (bf16)v;
        } else if (MODE == 2) {
          v += bias[nc] + resid[(size_t)mr * N + nc];
          ((float*)outP)[(size_t)mr * N + nc] = v;
        } else {
          v = fmaxf(v + bias[nc], 0.f);
          ((bf16*)outP)[(size_t)mr * N + nc] = (bf16)v;
        }
      }
    }
  }
}

extern "C" void kernel_launch(void* const* d_in, const int* in_sizes, int n_in,
                              void* d_out, int out_size, void* d_ws, size_t ws_size,
                              hipStream_t stream)
{
  (void)in_sizes; (void)n_in; (void)out_size; (void)ws_size;
  const float* msa = (const float*)d_in[0];
  const float* rr  = (const float*)d_in[1];
  const float* lmw = (const float*)d_in[2];
  const float* lmb = (const float*)d_in[3];
  const float* lrw = (const float*)d_in[4];
  const float* lrb = (const float*)d_in[5];
  const float* WA  = (const float*)d_in[6];
  // d_in[7] = bA: constant over the softmax (key) axis -> cancels exactly. Unused.
  const float* WV  = (const float*)d_in[8];
  const float* bV  = (const float*)d_in[9];
  const float* WO  = (const float*)d_in[10];
  const float* bO  = (const float*)d_in[11];
  const float* lfw = (const float*)d_in[12];
  const float* lfb = (const float*)d_in[13];
  const float* W1  = (const float*)d_in[14];
  const float* b1  = (const float*)d_in[15];
  const float* W2  = (const float*)d_in[16];
  const float* b2  = (const float*)d_in[17];
  float* out = (float*)d_out;
  char* ws = (char*)d_ws;
  // Workspace layout (85.2 MB); t aliases S/A/m/Vt/agg (all dead by FFN time).
  bf16* tbuf = (bf16*)(ws + 0);          // [32768][1024] bf16 = 67.1 MB
  float* S   = (float*)(ws + 0);         // [512][512][4] f32 = 4.2 MB
  bf16* Abuf = (bf16*)(ws + 4194304);    // [4][512][512] bf16 = 2.1 MB
  bf16* m    = (bf16*)(ws + 6291456);    // [32768][256] bf16 = 16.8 MB
  bf16* Vt   = (bf16*)(ws + 23068672);   // [4][4096][512] bf16 = 16.8 MB
  bf16* agg  = (bf16*)(ws + 39845888);   // [32768][256] bf16 = 16.8 MB
  bf16* h    = (bf16*)(ws + 67108864);   // [32768][256] bf16 = 16.8 MB
  bf16* WVt  = (bf16*)(ws + 83886080);   // transposed bf16 weights
  bf16* WOt  = WVt + 65536;
  bf16* W1t  = WOt + 65536;
  bf16* W2t  = W1t + 262144;

  dim3 tb(32, 8);
  transpose_f32_bf16<<<dim3(8, 8),  tb, 0, stream>>>(WV, WVt, 256, 256);
  transpose_f32_bf16<<<dim3(8, 8),  tb, 0, stream>>>(WO, WOt, 256, 256);
  transpose_f32_bf16<<<dim3(32, 8), tb, 0, stream>>>(W1, W1t, 256, 1024);
  transpose_f32_bf16<<<dim3(8, 32), tb, 0, stream>>>(W2, W2t, 1024, 256);

  // m = LN(msa) bf16
  ln_rows_kernel<<<8192, 256, 0, stream>>>(msa, lmw, lmb, m);
  // S[i,j,g] logits (symmetric), rr read once
  sym_ln_wa_kernel<<<dim3(528, 2), 256, 0, stream>>>(rr, lrw, lrb, WA, S);
  // Vt[g][d*64+c6][j] = (m @ WV + bV)^T, computed as WVt @ m^T
  gemm_bt_kernel<0><<<dim3(256, 2, 1), 256, 0, stream>>>(WVt, m, Vt, bV, nullptr, 256, 32768, 256);
  // A[g][i][j] softmax
  softmax_kernel<<<128, 256, 0, stream>>>(S, Abuf);
  // agg[(d,i)][g*64+c6] = sum_j A_g[i,j] * Vt_g[dc][j]
  gemm_bt_kernel<1><<<dim3(32, 4, 4), 256, 0, stream>>>(Abuf, Vt, agg, nullptr, nullptr, 512, 4096, 512);
  // x = agg @ WO + bO + msa  -> d_out (f32)
  gemm_bt_kernel<2><<<dim3(2, 256, 1), 256, 0, stream>>>(agg, WOt, out, bO, msa, 32768, 256, 256);
  // h = LN(x) bf16
  ln_rows_kernel<<<8192, 256, 0, stream>>>(out, lfw, lfb, h);
  // t = relu(h @ W1 + b1) bf16
  gemm_bt_kernel<3><<<dim3(8, 256, 1), 256, 0, stream>>>(h, W1t, tbuf, b1, nullptr, 32768, 1024, 256);
  // out = t @ W2 + b2 + x  (reads x from d_out, writes final output in place)
  gemm_bt_kernel<2><<<dim3(2, 256, 1), 256, 0, stream>>>(tbuf, W2t, out, b2, out, 32768, 256, 1024);
}

// Round 2
// 249.576 us; speedup vs baseline: 1.0343x; 1.0343x over previous
//
#include <hip/hip_runtime.h>
#include <hip/hip_bf16.h>

typedef __bf16 bf16;
typedef bf16 bf16x8 __attribute__((ext_vector_type(8)));
typedef bf16 bf16x4v __attribute__((ext_vector_type(4)));
typedef float f32x4 __attribute__((ext_vector_type(4)));

#define LN_EPS 1e-5f

// async global->LDS, 16 B per lane; LDS dest = wave-uniform base + lane*16
__device__ __forceinline__ void gload_lds16(const bf16* gsrc, bf16* ldst) {
  __builtin_amdgcn_global_load_lds(
      (const __attribute__((address_space(1))) void*)gsrc,
      (__attribute__((address_space(3))) void*)ldst, 16, 0, 0);
}

// ---------------- LayerNorm rows: f32 [R][256] -> bf16 [R][256] ----------------
__global__ __launch_bounds__(256) void ln_rows_kernel(
    const float* __restrict__ in, const float* __restrict__ w,
    const float* __restrict__ b, bf16* __restrict__ out)
{
  int row = blockIdx.x * 4 + (threadIdx.x >> 6);
  int lane = threadIdx.x & 63;
  const float4* p = (const float4*)(in + (size_t)row * 256);
  float4 v = p[lane];
  float s = v.x + v.y + v.z + v.w;
  float q = v.x*v.x + v.y*v.y + v.z*v.z + v.w*v.w;
  #pragma unroll
  for (int o = 32; o; o >>= 1) { s += __shfl_xor(s, o); q += __shfl_xor(q, o); }
  float mu = s * (1.0f/256.0f);
  float rs = rsqrtf(q*(1.0f/256.0f) - mu*mu + LN_EPS);
  float4 wv = ((const float4*)w)[lane];
  float4 bv = ((const float4*)b)[lane];
  bf16x4v o4;
  o4[0] = (bf16)((v.x - mu)*rs*wv.x + bv.x);
  o4[1] = (bf16)((v.y - mu)*rs*wv.y + bv.y);
  o4[2] = (bf16)((v.z - mu)*rs*wv.z + bv.z);
  o4[3] = (bf16)((v.w - mu)*rs*wv.w + bv.w);
  *(bf16x4v*)(out + (size_t)row * 256 + lane * 4) = o4;
}

// ------------- all 4 weight transposes in one dispatch: f32 [R][C] -> bf16 [C][R] -------------
__global__ __launch_bounds__(256) void transpose_all_kernel(
    const float* __restrict__ WV, const float* __restrict__ WO,
    const float* __restrict__ W1, const float* __restrict__ W2,
    bf16* __restrict__ WVt, bf16* __restrict__ WOt,
    bf16* __restrict__ W1t, bf16* __restrict__ W2t)
{
  __shared__ float tile[32][33];
  int id = blockIdx.x;
  const float* in; bf16* out; int R, C, tpr;
  if (id < 64)       { in = WV; out = WVt; R = 256;  C = 256;  tpr = 8;  }
  else if (id < 128) { in = WO; out = WOt; R = 256;  C = 256;  tpr = 8;  id -= 64; }
  else if (id < 384) { in = W1; out = W1t; R = 256;  C = 1024; tpr = 32; id -= 128; }
  else               { in = W2; out = W2t; R = 1024; C = 256;  tpr = 8;  id -= 384; }
  int bc = (id % tpr) * 32, br = (id / tpr) * 32;
  int tx = threadIdx.x, ty = threadIdx.y;
  #pragma unroll
  for (int i = ty; i < 32; i += 8)
    tile[i][tx] = in[(size_t)(br + i) * C + bc + tx];
  __syncthreads();
  #pragma unroll
  for (int i = ty; i < 32; i += 8)
    out[(size_t)(bc + i) * R + br + tx] = (bf16)tile[tx][i];
}

// ------- symmetrize + LN + WA: rr [512,512,256] -> S [i][j][4] f32 (symmetric) -------
// Each (i,j) pair with tile(ti<=tj) is computed once; rr read exactly once (276 MB).
__global__ __launch_bounds__(256) void sym_ln_wa_kernel(
    const float* __restrict__ rr, const float* __restrict__ w,
    const float* __restrict__ b, const float* __restrict__ WA,
    float* __restrict__ S)
{
  int rem = blockIdx.x; int ti = 0; int len = 32;
  while (rem >= len) { rem -= len; ti++; len--; }
  int tj = ti + rem;
  int wid = threadIdx.x >> 6, lane = threadIdx.x & 63;
  int c0 = lane * 4;
  float4 wv = ((const float4*)w)[lane];
  float4 bv = ((const float4*)b)[lane];
  const float4* wa4 = (const float4*)WA;   // WA[c][g], rows of 4 g
  float4 wa0 = wa4[c0+0], wa1 = wa4[c0+1], wa2 = wa4[c0+2], wa3 = wa4[c0+3];
  int pend = blockIdx.y * 64 + 64;
  for (int p = blockIdx.y * 64 + wid; p < pend; p += 4) {
    int i = ti*16 + (p >> 4), j = tj*16 + (p & 15);
    float4 a = ((const float4*)(rr + ((size_t)i*512 + j)*256))[lane];
    float4 c = ((const float4*)(rr + ((size_t)j*512 + i)*256))[lane];
    float ex = 0.5f*(a.x + c.x), ey = 0.5f*(a.y + c.y),
          ez = 0.5f*(a.z + c.z), ew = 0.5f*(a.w + c.w);
    float s = ex+ey+ez+ew;
    float q = ex*ex+ey*ey+ez*ez+ew*ew;
    #pragma unroll
    for (int o = 32; o; o >>= 1) { s += __shfl_xor(s, o); q += __shfl_xor(q, o); }
    float mu = s*(1.f/256.f);
    float rs = rsqrtf(q*(1.f/256.f) - mu*mu + LN_EPS);
    float nx = (ex-mu)*rs*wv.x + bv.x;
    float ny = (ey-mu)*rs*wv.y + bv.y;
    float nz = (ez-mu)*rs*wv.z + bv.z;
    float nw = (ew-mu)*rs*wv.w + bv.w;
    float g0 = nx*wa0.x + ny*wa1.x + nz*wa2.x + nw*wa3.x;
    float g1 = nx*wa0.y + ny*wa1.y + nz*wa2.y + nw*wa3.y;
    float g2 = nx*wa0.z + ny*wa1.z + nz*wa2.z + nw*wa3.z;
    float g3 = nx*wa0.w + ny*wa1.w + nz*wa2.w + nw*wa3.w;
    #pragma unroll
    for (int o = 32; o; o >>= 1) {
      g0 += __shfl_xor(g0, o); g1 += __shfl_xor(g1, o);
      g2 += __shfl_xor(g2, o); g3 += __shfl_xor(g3, o);
    }
    if (lane == 0) {
      float4 r4 = make_float4(g0, g1, g2, g3);  // bA omitted: cancels in softmax
      ((float4*)S)[(size_t)i*512 + j] = r4;
      ((float4*)S)[(size_t)j*512 + i] = r4;
    }
  }
}

// ---------------- softmax over j: S [i][j][4] f32 -> A bf16 [g][i][j] ----------------
__global__ __launch_bounds__(256) void softmax_kernel(
    const float* __restrict__ S, bf16* __restrict__ Aout)
{
  int i = blockIdx.x * 4 + (threadIdx.x >> 6);
  int lane = threadIdx.x & 63;
  const float4* Sr = (const float4*)S + (size_t)i * 512;
  float4 s[8];
  float m0 = -1e30f, m1 = -1e30f, m2 = -1e30f, m3 = -1e30f;
  #pragma unroll
  for (int it = 0; it < 8; it++) {
    s[it] = Sr[lane + it*64];
    m0 = fmaxf(m0, s[it].x); m1 = fmaxf(m1, s[it].y);
    m2 = fmaxf(m2, s[it].z); m3 = fmaxf(m3, s[it].w);
  }
  #pragma unroll
  for (int o = 32; o; o >>= 1) {
    m0 = fmaxf(m0, __shfl_xor(m0, o)); m1 = fmaxf(m1, __shfl_xor(m1, o));
    m2 = fmaxf(m2, __shfl_xor(m2, o)); m3 = fmaxf(m3, __shfl_xor(m3, o));
  }
  float t0=0.f, t1=0.f, t2=0.f, t3=0.f;
  #pragma unroll
  for (int it = 0; it < 8; it++) {
    s[it].x = __expf(s[it].x - m0); t0 += s[it].x;
    s[it].y = __expf(s[it].y - m1); t1 += s[it].y;
    s[it].z = __expf(s[it].z - m2); t2 += s[it].z;
    s[it].w = __expf(s[it].w - m3); t3 += s[it].w;
  }
  #pragma unroll
  for (int o = 32; o; o >>= 1) {
    t0 += __shfl_xor(t0, o); t1 += __shfl_xor(t1, o);
    t2 += __shfl_xor(t2, o); t3 += __shfl_xor(t3, o);
  }
  t0 = 1.f/t0; t1 = 1.f/t1; t2 = 1.f/t2; t3 = 1.f/t3;
  bf16* A0 = Aout + (size_t)i * 512;
  #pragma unroll
  for (int it = 0; it < 8; it++) {
    int j = lane + it*64;
    A0[j]          = (bf16)(s[it].x * t0);
    A0[262144 + j] = (bf16)(s[it].y * t1);
    A0[524288 + j] = (bf16)(s[it].z * t2);
    A0[786432 + j] = (bf16)(s[it].w * t3);
  }
}

// ---------------- m97-structure MFMA GEMM: C[M,N] = A[M,K] @ Bt[N,K]^T ----------------
// LDS tiles are LINEAR [128][32] bf16 (global_load_lds: wave-uniform base + lane*16B).
// MODE 0: Vt epilogue (bias per row=c, scatter to Vt[g][d*64+c6][j])
// MODE 1: agg epilogue (per-g, scatter to agg[(d*512+i)][g*64+c6])
// MODE 2: +bias[n] +resid, write f32
// MODE 3: relu(+bias[n]), write bf16
template<int MODE>
__global__ __launch_bounds__(256) void gemm_bt_kernel(
    const bf16* __restrict__ Aglob, const bf16* __restrict__ Bglob,
    void* __restrict__ outP, const float* __restrict__ bias,
    const float* __restrict__ resid, int M, int N, int K)
{
  __shared__ bf16 As[128 * 32];
  __shared__ bf16 Bs[128 * 32];
  int g = blockIdx.z;
  const bf16* Ag = Aglob;
  const bf16* Bg = Bglob;
  if (MODE == 1) { Ag += (size_t)g * 512 * 512; Bg += (size_t)g * 4096 * 512; }
  int bm = blockIdx.y * 128, bn = blockIdx.x * 128;
  int tid = threadIdx.x;
  int wid = tid >> 6, lane = tid & 63;
  int wm = (wid >> 1) * 64, wn = (wid & 1) * 64;
  f32x4 acc[4][4];
  #pragma unroll
  for (int mi = 0; mi < 4; mi++)
    #pragma unroll
    for (int ni = 0; ni < 4; ni++)
      acc[mi][ni] = (f32x4){0.f, 0.f, 0.f, 0.f};
  // staging: chunk c (0..7) = 16 rows x 32 cols; lane -> row c*16+(lane>>2), col (lane&3)*8
  int c0 = wid * 2, c1 = wid * 2 + 1;
  int srow = lane >> 2;
  int scol = (lane & 3) * 8;
  const bf16* a0 = &Ag[(size_t)(bm + c0*16 + srow) * K + scol];
  const bf16* a1 = &Ag[(size_t)(bm + c1*16 + srow) * K + scol];
  const bf16* b0 = &Bg[(size_t)(bn + c0*16 + srow) * K + scol];
  const bf16* b1 = &Bg[(size_t)(bn + c1*16 + srow) * K + scol];
  int fr = lane & 15, fk = (lane >> 4) * 8;
  for (int k0 = 0; k0 < K; k0 += 32) {
    __syncthreads();   // previous tile's ds_reads complete before overwrite
    gload_lds16(a0 + k0, &As[c0 * 512]);
    gload_lds16(a1 + k0, &As[c1 * 512]);
    gload_lds16(b0 + k0, &Bs[c0 * 512]);
    gload_lds16(b1 + k0, &Bs[c1 * 512]);
    __syncthreads();   // vmcnt(0) drain: LDS tile ready
    bf16x8 af[4], bf_[4];
    #pragma unroll
    for (int mi = 0; mi < 4; mi++) af[mi] = *(const bf16x8*)&As[(wm + mi*16 + fr) * 32 + fk];
    #pragma unroll
    for (int ni = 0; ni < 4; ni++) bf_[ni] = *(const bf16x8*)&Bs[(wn + ni*16 + fr) * 32 + fk];
    #pragma unroll
    for (int mi = 0; mi < 4; mi++)
      #pragma unroll
      for (int ni = 0; ni < 4; ni++)
        acc[mi][ni] = __builtin_amdgcn_mfma_f32_16x16x32_bf16(af[mi], bf_[ni], acc[mi][ni], 0, 0, 0);
  }
  int cn0 = lane & 15;
  int rq = (lane >> 4) * 4;
  #pragma unroll
  for (int mi = 0; mi < 4; mi++) {
    #pragma unroll
    for (int ni = 0; ni < 4; ni++) {
      int mb = bm + wm + mi*16 + rq;
      int nc = bn + wn + ni*16 + cn0;
      #pragma unroll
      for (int r = 0; r < 4; r++) {
        int mr = mb + r;
        float v = acc[mi][ni][r];
        if (MODE == 0) {
          v += bias[mr];
          int gg = mr >> 6, rp = mr & 63, d = nc >> 9, j = nc & 511;
          ((bf16*)outP)[((size_t)gg*4096 + d*64 + rp)*512 + j] = (bf16)v;
        } else if (MODE == 1) {
          int d = nc >> 6, c6 = nc & 63;
          ((bf16*)outP)[((size_t)d*512 + mr)*256 + g*64 + c6] = (bf16)v;
        } else if (MODE == 2) {
          v += bias[nc] + resid[(size_t)mr * N + nc];
          ((float*)outP)[(size_t)mr * N + nc] = v;
        } else {
          v = fmaxf(v + bias[nc], 0.f);
          ((bf16*)outP)[(size_t)mr * N + nc] = (bf16)v;
        }
      }
    }
  }
}

extern "C" void kernel_launch(void* const* d_in, const int* in_sizes, int n_in,
                              void* d_out, int out_size, void* d_ws, size_t ws_size,
                              hipStream_t stream)
{
  (void)in_sizes; (void)n_in; (void)out_size; (void)ws_size;
  const float* msa = (const float*)d_in[0];
  const float* rr  = (const float*)d_in[1];
  const float* lmw = (const float*)d_in[2];
  const float* lmb = (const float*)d_in[3];
  const float* lrw = (const float*)d_in[4];
  const float* lrb = (const float*)d_in[5];
  const float* WA  = (const float*)d_in[6];
  // d_in[7] = bA: constant over the softmax (key) axis -> cancels exactly. Unused.
  const float* WV  = (const float*)d_in[8];
  const float* bV  = (const float*)d_in[9];
  const float* WO  = (const float*)d_in[10];
  const float* bO  = (const float*)d_in[11];
  const float* lfw = (const float*)d_in[12];
  const float* lfb = (const float*)d_in[13];
  const float* W1  = (const float*)d_in[14];
  const float* b1  = (const float*)d_in[15];
  const float* W2  = (const float*)d_in[16];
  const float* b2  = (const float*)d_in[17];
  float* out = (float*)d_out;
  char* ws = (char*)d_ws;
  // Workspace layout (85.2 MB); t aliases S/A/m/Vt/agg (all dead by FFN time).
  bf16* tbuf = (bf16*)(ws + 0);          // [32768][1024] bf16 = 67.1 MB
  float* S   = (float*)(ws + 0);         // [512][512][4] f32 = 4.2 MB
  bf16* Abuf = (bf16*)(ws + 4194304);    // [4][512][512] bf16 = 2.1 MB
  bf16* m    = (bf16*)(ws + 6291456);    // [32768][256] bf16 = 16.8 MB
  bf16* Vt   = (bf16*)(ws + 23068672);   // [4][4096][512] bf16 = 16.8 MB
  bf16* agg  = (bf16*)(ws + 39845888);   // [32768][256] bf16 = 16.8 MB
  bf16* h    = (bf16*)(ws + 67108864);   // [32768][256] bf16 = 16.8 MB
  bf16* WVt  = (bf16*)(ws + 83886080);   // transposed bf16 weights
  bf16* WOt  = WVt + 65536;
  bf16* W1t  = WOt + 65536;
  bf16* W2t  = W1t + 262144;

  transpose_all_kernel<<<640, dim3(32, 8), 0, stream>>>(WV, WO, W1, W2, WVt, WOt, W1t, W2t);

  // m = LN(msa) bf16
  ln_rows_kernel<<<8192, 256, 0, stream>>>(msa, lmw, lmb, m);
  // S[i,j,g] logits (symmetric), rr read once
  sym_ln_wa_kernel<<<dim3(528, 4), 256, 0, stream>>>(rr, lrw, lrb, WA, S);
  // Vt[g][d*64+c6][j] = (m @ WV + bV)^T, computed as WVt @ m^T
  gemm_bt_kernel<0><<<dim3(256, 2, 1), 256, 0, stream>>>(WVt, m, Vt, bV, nullptr, 256, 32768, 256);
  // A[g][i][j] softmax
  softmax_kernel<<<128, 256, 0, stream>>>(S, Abuf);
  // agg[(d,i)][g*64+c6] = sum_j A_g[i,j] * Vt_g[dc][j]
  gemm_bt_kernel<1><<<dim3(32, 4, 4), 256, 0, stream>>>(Abuf, Vt, agg, nullptr, nullptr, 512, 4096, 512);
  // x = agg @ WO + bO + msa  -> d_out (f32)
  gemm_bt_kernel<2><<<dim3(2, 256, 1), 256, 0, stream>>>(agg, WOt, out, bO, msa, 32768, 256, 256);
  // h = LN(x) bf16
  ln_rows_kernel<<<8192, 256, 0, stream>>>(out, lfw, lfb, h);
  // t = relu(h @ W1 + b1) bf16
  gemm_bt_kernel<3><<<dim3(8, 256, 1), 256, 0, stream>>>(h, W1t, tbuf, b1, nullptr, 32768, 1024, 256);
  // out = t @ W2 + b2 + x  (reads x from d_out, writes final output in place)
  gemm_bt_kernel<2><<<dim3(2, 256, 1), 256, 0, stream>>>(tbuf, W2t, out, b2, out, 32768, 256, 1024);
}

// Round 3
// 242.892 us; speedup vs baseline: 1.0628x; 1.0275x over previous
//
#include <hip/hip_runtime.h>
#include <hip/hip_bf16.h>

typedef __bf16 bf16;
typedef bf16 bf16x8 __attribute__((ext_vector_type(8)));
typedef bf16 bf16x4v __attribute__((ext_vector_type(4)));
typedef float f32x4 __attribute__((ext_vector_type(4)));

#define LN_EPS 1e-5f

// async global->LDS, 16 B per lane; LDS dest = wave-uniform base + lane*16
__device__ __forceinline__ void gload_lds16(const bf16* gsrc, bf16* ldst) {
  __builtin_amdgcn_global_load_lds(
      (const __attribute__((address_space(1))) void*)gsrc,
      (__attribute__((address_space(3))) void*)ldst, 16, 0, 0);
}

// ---------------- LayerNorm rows: f32 [R][256] -> bf16 [R][256] ----------------
__global__ __launch_bounds__(256) void ln_rows_kernel(
    const float* __restrict__ in, const float* __restrict__ w,
    const float* __restrict__ b, bf16* __restrict__ out)
{
  int row = blockIdx.x * 4 + (threadIdx.x >> 6);
  int lane = threadIdx.x & 63;
  const float4* p = (const float4*)(in + (size_t)row * 256);
  float4 v = p[lane];
  float s = v.x + v.y + v.z + v.w;
  float q = v.x*v.x + v.y*v.y + v.z*v.z + v.w*v.w;
  #pragma unroll
  for (int o = 32; o; o >>= 1) { s += __shfl_xor(s, o); q += __shfl_xor(q, o); }
  float mu = s * (1.0f/256.0f);
  float rs = rsqrtf(q*(1.0f/256.0f) - mu*mu + LN_EPS);
  float4 wv = ((const float4*)w)[lane];
  float4 bv = ((const float4*)b)[lane];
  bf16x4v o4;
  o4[0] = (bf16)((v.x - mu)*rs*wv.x + bv.x);
  o4[1] = (bf16)((v.y - mu)*rs*wv.y + bv.y);
  o4[2] = (bf16)((v.z - mu)*rs*wv.z + bv.z);
  o4[3] = (bf16)((v.w - mu)*rs*wv.w + bv.w);
  *(bf16x4v*)(out + (size_t)row * 256 + lane * 4) = o4;
}

// ------------- all 4 weight transposes in one dispatch: f32 [R][C] -> bf16 [C][R] -------------
__global__ __launch_bounds__(256) void transpose_all_kernel(
    const float* __restrict__ WV, const float* __restrict__ WO,
    const float* __restrict__ W1, const float* __restrict__ W2,
    bf16* __restrict__ WVt, bf16* __restrict__ WOt,
    bf16* __restrict__ W1t, bf16* __restrict__ W2t)
{
  __shared__ float tile[32][33];
  int id = blockIdx.x;
  const float* in; bf16* out; int R, C, tpr;
  if (id < 64)       { in = WV; out = WVt; R = 256;  C = 256;  tpr = 8;  }
  else if (id < 128) { in = WO; out = WOt; R = 256;  C = 256;  tpr = 8;  id -= 64; }
  else if (id < 384) { in = W1; out = W1t; R = 256;  C = 1024; tpr = 32; id -= 128; }
  else               { in = W2; out = W2t; R = 1024; C = 256;  tpr = 8;  id -= 384; }
  int bc = (id % tpr) * 32, br = (id / tpr) * 32;
  int tx = threadIdx.x, ty = threadIdx.y;
  #pragma unroll
  for (int i = ty; i < 32; i += 8)
    tile[i][tx] = in[(size_t)(br + i) * C + bc + tx];
  __syncthreads();
  #pragma unroll
  for (int i = ty; i < 32; i += 8)
    out[(size_t)(bc + i) * R + br + tx] = (bf16)tile[tx][i];
}

// ------- symmetrize + LN + WA: rr [512,512,256] -> S [i][j][4] f32 (symmetric) -------
__global__ __launch_bounds__(256) void sym_ln_wa_kernel(
    const float* __restrict__ rr, const float* __restrict__ w,
    const float* __restrict__ b, const float* __restrict__ WA,
    float* __restrict__ S)
{
  int rem = blockIdx.x; int ti = 0; int len = 32;
  while (rem >= len) { rem -= len; ti++; len--; }
  int tj = ti + rem;
  int wid = threadIdx.x >> 6, lane = threadIdx.x & 63;
  int c0 = lane * 4;
  float4 wv = ((const float4*)w)[lane];
  float4 bv = ((const float4*)b)[lane];
  const float4* wa4 = (const float4*)WA;   // WA[c][g], rows of 4 g
  float4 wa0 = wa4[c0+0], wa1 = wa4[c0+1], wa2 = wa4[c0+2], wa3 = wa4[c0+3];
  int pend = blockIdx.y * 64 + 64;
  for (int p = blockIdx.y * 64 + wid; p < pend; p += 4) {
    int i = ti*16 + (p >> 4), j = tj*16 + (p & 15);
    float4 a = ((const float4*)(rr + ((size_t)i*512 + j)*256))[lane];
    float4 c = ((const float4*)(rr + ((size_t)j*512 + i)*256))[lane];
    float ex = 0.5f*(a.x + c.x), ey = 0.5f*(a.y + c.y),
          ez = 0.5f*(a.z + c.z), ew = 0.5f*(a.w + c.w);
    float s = ex+ey+ez+ew;
    float q = ex*ex+ey*ey+ez*ez+ew*ew;
    #pragma unroll
    for (int o = 32; o; o >>= 1) { s += __shfl_xor(s, o); q += __shfl_xor(q, o); }
    float mu = s*(1.f/256.f);
    float rs = rsqrtf(q*(1.f/256.f) - mu*mu + LN_EPS);
    float nx = (ex-mu)*rs*wv.x + bv.x;
    float ny = (ey-mu)*rs*wv.y + bv.y;
    float nz = (ez-mu)*rs*wv.z + bv.z;
    float nw = (ew-mu)*rs*wv.w + bv.w;
    float g0 = nx*wa0.x + ny*wa1.x + nz*wa2.x + nw*wa3.x;
    float g1 = nx*wa0.y + ny*wa1.y + nz*wa2.y + nw*wa3.y;
    float g2 = nx*wa0.z + ny*wa1.z + nz*wa2.z + nw*wa3.z;
    float g3 = nx*wa0.w + ny*wa1.w + nz*wa2.w + nw*wa3.w;
    #pragma unroll
    for (int o = 32; o; o >>= 1) {
      g0 += __shfl_xor(g0, o); g1 += __shfl_xor(g1, o);
      g2 += __shfl_xor(g2, o); g3 += __shfl_xor(g3, o);
    }
    if (lane == 0) {
      float4 r4 = make_float4(g0, g1, g2, g3);  // bA omitted: cancels in softmax
      ((float4*)S)[(size_t)i*512 + j] = r4;
      ((float4*)S)[(size_t)j*512 + i] = r4;
    }
  }
}

// ---------------- softmax over j: S [i][j][4] f32 -> A bf16 [g][i][j] ----------------
__global__ __launch_bounds__(256) void softmax_kernel(
    const float* __restrict__ S, bf16* __restrict__ Aout)
{
  int i = blockIdx.x * 4 + (threadIdx.x >> 6);
  int lane = threadIdx.x & 63;
  const float4* Sr = (const float4*)S + (size_t)i * 512;
  float4 s[8];
  float m0 = -1e30f, m1 = -1e30f, m2 = -1e30f, m3 = -1e30f;
  #pragma unroll
  for (int it = 0; it < 8; it++) {
    s[it] = Sr[lane + it*64];
    m0 = fmaxf(m0, s[it].x); m1 = fmaxf(m1, s[it].y);
    m2 = fmaxf(m2, s[it].z); m3 = fmaxf(m3, s[it].w);
  }
  #pragma unroll
  for (int o = 32; o; o >>= 1) {
    m0 = fmaxf(m0, __shfl_xor(m0, o)); m1 = fmaxf(m1, __shfl_xor(m1, o));
    m2 = fmaxf(m2, __shfl_xor(m2, o)); m3 = fmaxf(m3, __shfl_xor(m3, o));
  }
  float t0=0.f, t1=0.f, t2=0.f, t3=0.f;
  #pragma unroll
  for (int it = 0; it < 8; it++) {
    s[it].x = __expf(s[it].x - m0); t0 += s[it].x;
    s[it].y = __expf(s[it].y - m1); t1 += s[it].y;
    s[it].z = __expf(s[it].z - m2); t2 += s[it].z;
    s[it].w = __expf(s[it].w - m3); t3 += s[it].w;
  }
  #pragma unroll
  for (int o = 32; o; o >>= 1) {
    t0 += __shfl_xor(t0, o); t1 += __shfl_xor(t1, o);
    t2 += __shfl_xor(t2, o); t3 += __shfl_xor(t3, o);
  }
  t0 = 1.f/t0; t1 = 1.f/t1; t2 = 1.f/t2; t3 = 1.f/t3;
  bf16* A0 = Aout + (size_t)i * 512;
  #pragma unroll
  for (int it = 0; it < 8; it++) {
    int j = lane + it*64;
    A0[j]          = (bf16)(s[it].x * t0);
    A0[262144 + j] = (bf16)(s[it].y * t1);
    A0[524288 + j] = (bf16)(s[it].z * t2);
    A0[786432 + j] = (bf16)(s[it].w * t3);
  }
}

// ---------------- m97-structure MFMA GEMM: C[M,N] = A[M,K] @ Bt[N,K]^T ----------------
// MODE 0: Vt epilogue; MODE 1: agg epilogue; MODE 2: +bias[n]+resid, f32 out
template<int MODE>
__global__ __launch_bounds__(256) void gemm_bt_kernel(
    const bf16* __restrict__ Aglob, const bf16* __restrict__ Bglob,
    void* __restrict__ outP, const float* __restrict__ bias,
    const float* __restrict__ resid, int M, int N, int K)
{
  __shared__ bf16 As[128 * 32];
  __shared__ bf16 Bs[128 * 32];
  int g = blockIdx.z;
  const bf16* Ag = Aglob;
  const bf16* Bg = Bglob;
  if (MODE == 1) { Ag += (size_t)g * 512 * 512; Bg += (size_t)g * 4096 * 512; }
  int bm = blockIdx.y * 128, bn = blockIdx.x * 128;
  int tid = threadIdx.x;
  int wid = tid >> 6, lane = tid & 63;
  int wm = (wid >> 1) * 64, wn = (wid & 1) * 64;
  f32x4 acc[4][4];
  #pragma unroll
  for (int mi = 0; mi < 4; mi++)
    #pragma unroll
    for (int ni = 0; ni < 4; ni++)
      acc[mi][ni] = (f32x4){0.f, 0.f, 0.f, 0.f};
  int c0 = wid * 2, c1 = wid * 2 + 1;
  int srow = lane >> 2;
  int scol = (lane & 3) * 8;
  const bf16* a0 = &Ag[(size_t)(bm + c0*16 + srow) * K + scol];
  const bf16* a1 = &Ag[(size_t)(bm + c1*16 + srow) * K + scol];
  const bf16* b0 = &Bg[(size_t)(bn + c0*16 + srow) * K + scol];
  const bf16* b1 = &Bg[(size_t)(bn + c1*16 + srow) * K + scol];
  int fr = lane & 15, fk = (lane >> 4) * 8;
  for (int k0 = 0; k0 < K; k0 += 32) {
    __syncthreads();
    gload_lds16(a0 + k0, &As[c0 * 512]);
    gload_lds16(a1 + k0, &As[c1 * 512]);
    gload_lds16(b0 + k0, &Bs[c0 * 512]);
    gload_lds16(b1 + k0, &Bs[c1 * 512]);
    __syncthreads();
    bf16x8 af[4], bf_[4];
    #pragma unroll
    for (int mi = 0; mi < 4; mi++) af[mi] = *(const bf16x8*)&As[(wm + mi*16 + fr) * 32 + fk];
    #pragma unroll
    for (int ni = 0; ni < 4; ni++) bf_[ni] = *(const bf16x8*)&Bs[(wn + ni*16 + fr) * 32 + fk];
    #pragma unroll
    for (int mi = 0; mi < 4; mi++)
      #pragma unroll
      for (int ni = 0; ni < 4; ni++)
        acc[mi][ni] = __builtin_amdgcn_mfma_f32_16x16x32_bf16(af[mi], bf_[ni], acc[mi][ni], 0, 0, 0);
  }
  int cn0 = lane & 15;
  int rq = (lane >> 4) * 4;
  #pragma unroll
  for (int mi = 0; mi < 4; mi++) {
    #pragma unroll
    for (int ni = 0; ni < 4; ni++) {
      int mb = bm + wm + mi*16 + rq;
      int nc = bn + wn + ni*16 + cn0;
      #pragma unroll
      for (int r = 0; r < 4; r++) {
        int mr = mb + r;
        float v = acc[mi][ni][r];
        if (MODE == 0) {
          v += bias[mr];
          int gg = mr >> 6, rp = mr & 63, d = nc >> 9, j = nc & 511;
          ((bf16*)outP)[((size_t)gg*4096 + d*64 + rp)*512 + j] = (bf16)v;
        } else if (MODE == 1) {
          int d = nc >> 6, c6 = nc & 63;
          ((bf16*)outP)[((size_t)d*512 + mr)*256 + g*64 + c6] = (bf16)v;
        } else {
          v += bias[nc] + resid[(size_t)mr * N + nc];
          ((float*)outP)[(size_t)mr * N + nc] = v;
        }
      }
    }
  }
}

// ========== fused FFN: out = x + relu(LN(x)@W1 + b1)@W2 + b2 ==========
// One block per 128 rows; h and t resident in LDS (XOR-swizzled);
// W1t/W2t stream through a 16 KB linear LDS buffer via gload_lds with
// pre-swizzled global source (rule #21).
__global__ __launch_bounds__(512, 2) void ffn_fused_kernel(
    const float* __restrict__ x, const float* __restrict__ lnw,
    const float* __restrict__ lnb, const bf16* __restrict__ W1t,
    const float* __restrict__ b1, const bf16* __restrict__ W2t,
    const float* __restrict__ b2, float* __restrict__ out)
{
  __shared__ __align__(16) char hbuf[128 * 512];   // bf16 [128][256] swizzled
  __shared__ __align__(16) char tbuf[128 * 512];   // bf16 [128][256] swizzled
  __shared__ __align__(16) bf16 Bs[256 * 32];      // B staging, row-sliced swizzle
  int tid = threadIdx.x;
  int wid = tid >> 6, lane = tid & 63;
  size_t row0 = (size_t)blockIdx.x * 128;

  // ---- LN(x) -> hbuf ----
  {
    float4 wv = ((const float4*)lnw)[lane];
    float4 bv = ((const float4*)lnb)[lane];
    for (int it = 0; it < 16; it++) {
      int row = wid * 16 + it;
      float4 v = ((const float4*)(x + (row0 + row) * 256))[lane];
      float s = v.x+v.y+v.z+v.w, q = v.x*v.x+v.y*v.y+v.z*v.z+v.w*v.w;
      #pragma unroll
      for (int o = 32; o; o >>= 1) { s += __shfl_xor(s, o); q += __shfl_xor(q, o); }
      float mu = s * (1.f/256.f);
      float rs = rsqrtf(q*(1.f/256.f) - mu*mu + LN_EPS);
      bf16x4v o4;
      o4[0] = (bf16)((v.x-mu)*rs*wv.x + bv.x);
      o4[1] = (bf16)((v.y-mu)*rs*wv.y + bv.y);
      o4[2] = (bf16)((v.z-mu)*rs*wv.z + bv.z);
      o4[3] = (bf16)((v.w-mu)*rs*wv.w + bv.w);
      *(bf16x4v*)(hbuf + row*512 + ((lane*8) ^ ((row & 7) << 4))) = o4;
    }
  }
  __syncthreads();

  int wm = (wid >> 2) * 64;        // 0 / 64
  int wn = (wid & 3) * 64;         // 0..192
  int fr = lane & 15;
  int fk2 = ((lane >> 4) * 8) * 2; // k byte offset within row: 0/16/32/48
  int cn0 = lane & 15, rq = (lane >> 4) * 4;
  // A-fragment rows + swizzle keys
  int arow[4], asw[4], boff[4];
  #pragma unroll
  for (int mi = 0; mi < 4; mi++) {
    arow[mi] = wm + mi*16 + fr;
    asw[mi]  = (arow[mi] & 7) << 4;
  }
  #pragma unroll
  for (int ni = 0; ni < 4; ni++) {
    int br = wn + ni*16 + fr;
    boff[ni] = br*64 + (fk2 ^ (((br >> 1) & 3) << 4));
  }
  // staging identity: thread -> (row within 128, phys slot)
  int srow = tid >> 2;
  int ps = tid & 3;

  f32x4 acc2[4][4];
  #pragma unroll
  for (int mi = 0; mi < 4; mi++)
    #pragma unroll
    for (int ni = 0; ni < 4; ni++)
      acc2[mi][ni] = (f32x4){0.f, 0.f, 0.f, 0.f};

  for (int cf = 0; cf < 4; cf++) {
    // ---- GEMM1: acc1 = h @ W1t[cf*256 + n][k], K = 256 ----
    f32x4 acc1[4][4];
    #pragma unroll
    for (int mi = 0; mi < 4; mi++)
      #pragma unroll
      for (int ni = 0; ni < 4; ni++)
        acc1[mi][ni] = (f32x4){0.f, 0.f, 0.f, 0.f};
    for (int k0 = 0; k0 < 256; k0 += 32) {
      __syncthreads();
      #pragma unroll
      for (int q = 0; q < 2; q++) {
        int r = q*128 + srow;
        int ls = ps ^ ((r >> 1) & 3);
        gload_lds16(W1t + (size_t)(cf*256 + r) * 256 + k0 + ls*8,
                    Bs + q*4096 + wid*512);
      }
      __syncthreads();
      bf16x8 af[4], bf_[4];
      #pragma unroll
      for (int mi = 0; mi < 4; mi++)
        af[mi] = *(const bf16x8*)(hbuf + arow[mi]*512 + ((k0*2 + fk2) ^ asw[mi]));
      #pragma unroll
      for (int ni = 0; ni < 4; ni++)
        bf_[ni] = *(const bf16x8*)((const char*)Bs + boff[ni]);
      #pragma unroll
      for (int mi = 0; mi < 4; mi++)
        #pragma unroll
        for (int ni = 0; ni < 4; ni++)
          acc1[mi][ni] = __builtin_amdgcn_mfma_f32_16x16x32_bf16(af[mi], bf_[ni], acc1[mi][ni], 0, 0, 0);
    }
    // ---- t = relu(acc1 + b1) -> tbuf ----
    __syncthreads();   // previous chunk's GEMM2 done reading tbuf
    #pragma unroll
    for (int ni = 0; ni < 4; ni++) {
      int col = wn + ni*16 + cn0;
      float bb = b1[cf*256 + col];
      #pragma unroll
      for (int mi = 0; mi < 4; mi++) {
        #pragma unroll
        for (int r = 0; r < 4; r++) {
          int row = wm + mi*16 + rq + r;
          float v = fmaxf(acc1[mi][ni][r] + bb, 0.f);
          *(bf16*)(tbuf + row*512 + ((col*2) ^ ((row & 7) << 4))) = (bf16)v;
        }
      }
    }
    // ---- GEMM2: acc2 += t @ W2t[n][cf*256 + k], K = 256 ----
    for (int k0 = 0; k0 < 256; k0 += 32) {
      __syncthreads();   // t writes visible / Bs readers done
      #pragma unroll
      for (int q = 0; q < 2; q++) {
        int r = q*128 + srow;
        int ls = ps ^ ((r >> 1) & 3);
        gload_lds16(W2t + (size_t)r * 1024 + cf*256 + k0 + ls*8,
                    Bs + q*4096 + wid*512);
      }
      __syncthreads();
      bf16x8 af[4], bf_[4];
      #pragma unroll
      for (int mi = 0; mi < 4; mi++)
        af[mi] = *(const bf16x8*)(tbuf + arow[mi]*512 + ((k0*2 + fk2) ^ asw[mi]));
      #pragma unroll
      for (int ni = 0; ni < 4; ni++)
        bf_[ni] = *(const bf16x8*)((const char*)Bs + boff[ni]);
      #pragma unroll
      for (int mi = 0; mi < 4; mi++)
        #pragma unroll
        for (int ni = 0; ni < 4; ni++)
          acc2[mi][ni] = __builtin_amdgcn_mfma_f32_16x16x32_bf16(af[mi], bf_[ni], acc2[mi][ni], 0, 0, 0);
    }
  }
  // ---- epilogue: out = x + acc2 + b2 ----
  #pragma unroll
  for (int ni = 0; ni < 4; ni++) {
    int col = wn + ni*16 + cn0;
    float bb = b2[col];
    #pragma unroll
    for (int mi = 0; mi < 4; mi++) {
      #pragma unroll
      for (int r = 0; r < 4; r++) {
        size_t grow = row0 + wm + mi*16 + rq + r;
        out[grow*256 + col] = x[grow*256 + col] + acc2[mi][ni][r] + bb;
      }
    }
  }
}

extern "C" void kernel_launch(void* const* d_in, const int* in_sizes, int n_in,
                              void* d_out, int out_size, void* d_ws, size_t ws_size,
                              hipStream_t stream)
{
  (void)in_sizes; (void)n_in; (void)out_size; (void)ws_size;
  const float* msa = (const float*)d_in[0];
  const float* rr  = (const float*)d_in[1];
  const float* lmw = (const float*)d_in[2];
  const float* lmb = (const float*)d_in[3];
  const float* lrw = (const float*)d_in[4];
  const float* lrb = (const float*)d_in[5];
  const float* WA  = (const float*)d_in[6];
  // d_in[7] = bA: constant over the softmax (key) axis -> cancels exactly. Unused.
  const float* WV  = (const float*)d_in[8];
  const float* bV  = (const float*)d_in[9];
  const float* WO  = (const float*)d_in[10];
  const float* bO  = (const float*)d_in[11];
  const float* lfw = (const float*)d_in[12];
  const float* lfb = (const float*)d_in[13];
  const float* W1  = (const float*)d_in[14];
  const float* b1  = (const float*)d_in[15];
  const float* W2  = (const float*)d_in[16];
  const float* b2  = (const float*)d_in[17];
  float* out = (float*)d_out;
  char* ws = (char*)d_ws;
  float* S   = (float*)(ws + 0);         // [512][512][4] f32 = 4.2 MB
  bf16* Abuf = (bf16*)(ws + 4194304);    // [4][512][512] bf16 = 2.1 MB
  bf16* m    = (bf16*)(ws + 6291456);    // [32768][256] bf16 = 16.8 MB
  bf16* Vt   = (bf16*)(ws + 23068672);   // [4][4096][512] bf16 = 16.8 MB
  bf16* agg  = (bf16*)(ws + 39845888);   // [32768][256] bf16 = 16.8 MB
  bf16* WVt  = (bf16*)(ws + 83886080);   // transposed bf16 weights
  bf16* WOt  = WVt + 65536;
  bf16* W1t  = WOt + 65536;
  bf16* W2t  = W1t + 262144;

  transpose_all_kernel<<<640, dim3(32, 8), 0, stream>>>(WV, WO, W1, W2, WVt, WOt, W1t, W2t);

  // m = LN(msa) bf16
  ln_rows_kernel<<<8192, 256, 0, stream>>>(msa, lmw, lmb, m);
  // S[i,j,g] logits (symmetric), rr read once
  sym_ln_wa_kernel<<<dim3(528, 4), 256, 0, stream>>>(rr, lrw, lrb, WA, S);
  // Vt[g][d*64+c6][j] = (m @ WV + bV)^T, computed as WVt @ m^T
  gemm_bt_kernel<0><<<dim3(256, 2, 1), 256, 0, stream>>>(WVt, m, Vt, bV, nullptr, 256, 32768, 256);
  // A[g][i][j] softmax
  softmax_kernel<<<128, 256, 0, stream>>>(S, Abuf);
  // agg[(d,i)][g*64+c6] = sum_j A_g[i,j] * Vt_g[dc][j]
  gemm_bt_kernel<1><<<dim3(32, 4, 4), 256, 0, stream>>>(Abuf, Vt, agg, nullptr, nullptr, 512, 4096, 512);
  // x = agg @ WO + bO + msa  -> d_out (f32)
  gemm_bt_kernel<2><<<dim3(2, 256, 1), 256, 0, stream>>>(agg, WOt, out, bO, msa, 32768, 256, 256);
  // out = x + relu(LN(x)@W1+b1)@W2 + b2   (fused FFN, in place on d_out)
  ffn_fused_kernel<<<256, 512, 0, stream>>>(out, lfw, lfb, W1t, b1, W2t, b2, out);
}

// Round 4
// 242.068 us; speedup vs baseline: 1.0664x; 1.0034x over previous
//
#include <hip/hip_runtime.h>
#include <hip/hip_bf16.h>

typedef __bf16 bf16;
typedef bf16 bf16x8 __attribute__((ext_vector_type(8)));
typedef bf16 bf16x4v __attribute__((ext_vector_type(4)));
typedef float f32x4 __attribute__((ext_vector_type(4)));

#define LN_EPS 1e-5f

// async global->LDS, 16 B per lane; LDS dest = wave-uniform base + lane*16
__device__ __forceinline__ void gload_lds16(const bf16* gsrc, bf16* ldst) {
  __builtin_amdgcn_global_load_lds(
      (const __attribute__((address_space(1))) void*)gsrc,
      (__attribute__((address_space(3))) void*)ldst, 16, 0, 0);
}

// ---------------- LayerNorm rows: f32 [R][256] -> bf16 [R][256] ----------------
__global__ __launch_bounds__(256) void ln_rows_kernel(
    const float* __restrict__ in, const float* __restrict__ w,
    const float* __restrict__ b, bf16* __restrict__ out)
{
  int row = blockIdx.x * 4 + (threadIdx.x >> 6);
  int lane = threadIdx.x & 63;
  const float4* p = (const float4*)(in + (size_t)row * 256);
  float4 v = p[lane];
  float s = v.x + v.y + v.z + v.w;
  float q = v.x*v.x + v.y*v.y + v.z*v.z + v.w*v.w;
  #pragma unroll
  for (int o = 32; o; o >>= 1) { s += __shfl_xor(s, o); q += __shfl_xor(q, o); }
  float mu = s * (1.0f/256.0f);
  float rs = rsqrtf(q*(1.0f/256.0f) - mu*mu + LN_EPS);
  float4 wv = ((const float4*)w)[lane];
  float4 bv = ((const float4*)b)[lane];
  bf16x4v o4;
  o4[0] = (bf16)((v.x - mu)*rs*wv.x + bv.x);
  o4[1] = (bf16)((v.y - mu)*rs*wv.y + bv.y);
  o4[2] = (bf16)((v.z - mu)*rs*wv.z + bv.z);
  o4[3] = (bf16)((v.w - mu)*rs*wv.w + bv.w);
  *(bf16x4v*)(out + (size_t)row * 256 + lane * 4) = o4;
}

// ------------- all 4 weight transposes in one dispatch: f32 [R][C] -> bf16 [C][R] -------------
__global__ __launch_bounds__(256) void transpose_all_kernel(
    const float* __restrict__ WV, const float* __restrict__ WO,
    const float* __restrict__ W1, const float* __restrict__ W2,
    bf16* __restrict__ WVt, bf16* __restrict__ WOt,
    bf16* __restrict__ W1t, bf16* __restrict__ W2t)
{
  __shared__ float tile[32][33];
  int id = blockIdx.x;
  const float* in; bf16* out; int R, C, tpr;
  if (id < 64)       { in = WV; out = WVt; R = 256;  C = 256;  tpr = 8;  }
  else if (id < 128) { in = WO; out = WOt; R = 256;  C = 256;  tpr = 8;  id -= 64; }
  else if (id < 384) { in = W1; out = W1t; R = 256;  C = 1024; tpr = 32; id -= 128; }
  else               { in = W2; out = W2t; R = 1024; C = 256;  tpr = 8;  id -= 384; }
  int bc = (id % tpr) * 32, br = (id / tpr) * 32;
  int tx = threadIdx.x, ty = threadIdx.y;
  #pragma unroll
  for (int i = ty; i < 32; i += 8)
    tile[i][tx] = in[(size_t)(br + i) * C + bc + tx];
  __syncthreads();
  #pragma unroll
  for (int i = ty; i < 32; i += 8)
    out[(size_t)(bc + i) * R + br + tx] = (bf16)tile[tx][i];
}

// ------- symmetrize + LN + WA: rr [512,512,256] -> S [i][j][4] f32 (symmetric) -------
__global__ __launch_bounds__(256) void sym_ln_wa_kernel(
    const float* __restrict__ rr, const float* __restrict__ w,
    const float* __restrict__ b, const float* __restrict__ WA,
    float* __restrict__ S)
{
  int rem = blockIdx.x; int ti = 0; int len = 32;
  while (rem >= len) { rem -= len; ti++; len--; }
  int tj = ti + rem;
  int wid = threadIdx.x >> 6, lane = threadIdx.x & 63;
  int c0 = lane * 4;
  float4 wv = ((const float4*)w)[lane];
  float4 bv = ((const float4*)b)[lane];
  const float4* wa4 = (const float4*)WA;   // WA[c][g], rows of 4 g
  float4 wa0 = wa4[c0+0], wa1 = wa4[c0+1], wa2 = wa4[c0+2], wa3 = wa4[c0+3];
  int pend = blockIdx.y * 64 + 64;
  for (int p = blockIdx.y * 64 + wid; p < pend; p += 4) {
    int i = ti*16 + (p >> 4), j = tj*16 + (p & 15);
    float4 a = ((const float4*)(rr + ((size_t)i*512 + j)*256))[lane];
    float4 c = ((const float4*)(rr + ((size_t)j*512 + i)*256))[lane];
    float ex = 0.5f*(a.x + c.x), ey = 0.5f*(a.y + c.y),
          ez = 0.5f*(a.z + c.z), ew = 0.5f*(a.w + c.w);
    float s = ex+ey+ez+ew;
    float q = ex*ex+ey*ey+ez*ez+ew*ew;
    #pragma unroll
    for (int o = 32; o; o >>= 1) { s += __shfl_xor(s, o); q += __shfl_xor(q, o); }
    float mu = s*(1.f/256.f);
    float rs = rsqrtf(q*(1.f/256.f) - mu*mu + LN_EPS);
    float nx = (ex-mu)*rs*wv.x + bv.x;
    float ny = (ey-mu)*rs*wv.y + bv.y;
    float nz = (ez-mu)*rs*wv.z + bv.z;
    float nw = (ew-mu)*rs*wv.w + bv.w;
    float g0 = nx*wa0.x + ny*wa1.x + nz*wa2.x + nw*wa3.x;
    float g1 = nx*wa0.y + ny*wa1.y + nz*wa2.y + nw*wa3.y;
    float g2 = nx*wa0.z + ny*wa1.z + nz*wa2.z + nw*wa3.z;
    float g3 = nx*wa0.w + ny*wa1.w + nz*wa2.w + nw*wa3.w;
    #pragma unroll
    for (int o = 32; o; o >>= 1) {
      g0 += __shfl_xor(g0, o); g1 += __shfl_xor(g1, o);
      g2 += __shfl_xor(g2, o); g3 += __shfl_xor(g3, o);
    }
    if (lane == 0) {
      float4 r4 = make_float4(g0, g1, g2, g3);  // bA omitted: cancels in softmax
      ((float4*)S)[(size_t)i*512 + j] = r4;
      ((float4*)S)[(size_t)j*512 + i] = r4;
    }
  }
}

// ---------------- softmax over j: S [i][j][4] f32 -> A bf16 [g][i][j] ----------------
__global__ __launch_bounds__(256) void softmax_kernel(
    const float* __restrict__ S, bf16* __restrict__ Aout)
{
  int i = blockIdx.x * 4 + (threadIdx.x >> 6);
  int lane = threadIdx.x & 63;
  const float4* Sr = (const float4*)S + (size_t)i * 512;
  float4 s[8];
  float m0 = -1e30f, m1 = -1e30f, m2 = -1e30f, m3 = -1e30f;
  #pragma unroll
  for (int it = 0; it < 8; it++) {
    s[it] = Sr[lane + it*64];
    m0 = fmaxf(m0, s[it].x); m1 = fmaxf(m1, s[it].y);
    m2 = fmaxf(m2, s[it].z); m3 = fmaxf(m3, s[it].w);
  }
  #pragma unroll
  for (int o = 32; o; o >>= 1) {
    m0 = fmaxf(m0, __shfl_xor(m0, o)); m1 = fmaxf(m1, __shfl_xor(m1, o));
    m2 = fmaxf(m2, __shfl_xor(m2, o)); m3 = fmaxf(m3, __shfl_xor(m3, o));
  }
  float t0=0.f, t1=0.f, t2=0.f, t3=0.f;
  #pragma unroll
  for (int it = 0; it < 8; it++) {
    s[it].x = __expf(s[it].x - m0); t0 += s[it].x;
    s[it].y = __expf(s[it].y - m1); t1 += s[it].y;
    s[it].z = __expf(s[it].z - m2); t2 += s[it].z;
    s[it].w = __expf(s[it].w - m3); t3 += s[it].w;
  }
  #pragma unroll
  for (int o = 32; o; o >>= 1) {
    t0 += __shfl_xor(t0, o); t1 += __shfl_xor(t1, o);
    t2 += __shfl_xor(t2, o); t3 += __shfl_xor(t3, o);
  }
  t0 = 1.f/t0; t1 = 1.f/t1; t2 = 1.f/t2; t3 = 1.f/t3;
  bf16* A0 = Aout + (size_t)i * 512;
  #pragma unroll
  for (int it = 0; it < 8; it++) {
    int j = lane + it*64;
    A0[j]          = (bf16)(s[it].x * t0);
    A0[262144 + j] = (bf16)(s[it].y * t1);
    A0[524288 + j] = (bf16)(s[it].z * t2);
    A0[786432 + j] = (bf16)(s[it].w * t3);
  }
}

// ---------------- 2-phase pipelined MFMA GEMM: C[M,N] = A[M,K] @ Bt[N,K]^T ----------------
// Double-buffered LDS + counted vmcnt(4) + raw barriers (T3/T4 minimum recipe).
// MODE 0: Vt epilogue; MODE 1: agg epilogue; MODE 2: +bias[n]+resid, f32 out
template<int MODE>
__global__ __launch_bounds__(256) void gemm_bt_kernel(
    const bf16* __restrict__ Aglob, const bf16* __restrict__ Bglob,
    void* __restrict__ outP, const float* __restrict__ bias,
    const float* __restrict__ resid, int M, int N, int K)
{
  __shared__ bf16 As[2][128 * 32];
  __shared__ bf16 Bs[2][128 * 32];
  int g = blockIdx.z;
  const bf16* Ag = Aglob;
  const bf16* Bg = Bglob;
  if (MODE == 1) { Ag += (size_t)g * 512 * 512; Bg += (size_t)g * 4096 * 512; }
  int bm = blockIdx.y * 128, bn = blockIdx.x * 128;
  int tid = threadIdx.x;
  int wid = tid >> 6, lane = tid & 63;
  int wm = (wid >> 1) * 64, wn = (wid & 1) * 64;
  f32x4 acc[4][4];
  #pragma unroll
  for (int mi = 0; mi < 4; mi++)
    #pragma unroll
    for (int ni = 0; ni < 4; ni++)
      acc[mi][ni] = (f32x4){0.f, 0.f, 0.f, 0.f};
  int c0 = wid * 2, c1 = wid * 2 + 1;
  int srow = lane >> 2;
  int scol = (lane & 3) * 8;
  const bf16* a0 = &Ag[(size_t)(bm + c0*16 + srow) * K + scol];
  const bf16* a1 = &Ag[(size_t)(bm + c1*16 + srow) * K + scol];
  const bf16* b0 = &Bg[(size_t)(bn + c0*16 + srow) * K + scol];
  const bf16* b1 = &Bg[(size_t)(bn + c1*16 + srow) * K + scol];
  int fr = lane & 15, fk = (lane >> 4) * 8;
  int nt = K >> 5;
  // prologue: stage tile 0 into buf 0
  gload_lds16(a0, &As[0][c0 * 512]);
  gload_lds16(a1, &As[0][c1 * 512]);
  gload_lds16(b0, &Bs[0][c0 * 512]);
  gload_lds16(b1, &Bs[0][c1 * 512]);
  int cur = 0;
  for (int t = 0; t < nt; t++) {
    if (t + 1 < nt) {
      int k1 = (t + 1) << 5;
      gload_lds16(a0 + k1, &As[cur ^ 1][c0 * 512]);
      gload_lds16(a1 + k1, &As[cur ^ 1][c1 * 512]);
      gload_lds16(b0 + k1, &Bs[cur ^ 1][c0 * 512]);
      gload_lds16(b1 + k1, &Bs[cur ^ 1][c1 * 512]);
      asm volatile("s_waitcnt vmcnt(4)" ::: "memory");  // tile t landed; t+1 in flight
    } else {
      asm volatile("s_waitcnt vmcnt(0)" ::: "memory");
    }
    __builtin_amdgcn_s_barrier();           // all waves: tile t visible
    __builtin_amdgcn_sched_barrier(0);
    bf16x8 af[4], bf_[4];
    #pragma unroll
    for (int mi = 0; mi < 4; mi++) af[mi] = *(const bf16x8*)&As[cur][(wm + mi*16 + fr) * 32 + fk];
    #pragma unroll
    for (int ni = 0; ni < 4; ni++) bf_[ni] = *(const bf16x8*)&Bs[cur][(wn + ni*16 + fr) * 32 + fk];
    #pragma unroll
    for (int mi = 0; mi < 4; mi++)
      #pragma unroll
      for (int ni = 0; ni < 4; ni++)
        acc[mi][ni] = __builtin_amdgcn_mfma_f32_16x16x32_bf16(af[mi], bf_[ni], acc[mi][ni], 0, 0, 0);
    __builtin_amdgcn_sched_barrier(0);
    __builtin_amdgcn_s_barrier();           // all waves done reading buf[cur]
    cur ^= 1;
  }
  int cn0 = lane & 15;
  int rq = (lane >> 4) * 4;
  #pragma unroll
  for (int mi = 0; mi < 4; mi++) {
    #pragma unroll
    for (int ni = 0; ni < 4; ni++) {
      int mb = bm + wm + mi*16 + rq;
      int nc = bn + wn + ni*16 + cn0;
      #pragma unroll
      for (int r = 0; r < 4; r++) {
        int mr = mb + r;
        float v = acc[mi][ni][r];
        if (MODE == 0) {
          v += bias[mr];
          int gg = mr >> 6, rp = mr & 63, d = nc >> 9, j = nc & 511;
          ((bf16*)outP)[((size_t)gg*4096 + d*64 + rp)*512 + j] = (bf16)v;
        } else if (MODE == 1) {
          int d = nc >> 6, c6 = nc & 63;
          ((bf16*)outP)[((size_t)d*512 + mr)*256 + g*64 + c6] = (bf16)v;
        } else {
          v += bias[nc] + resid[(size_t)mr * N + nc];
          ((float*)outP)[(size_t)mr * N + nc] = v;
        }
      }
    }
  }
}

// ========== fused FFN: out = x + relu(LN(x)@W1 + b1)@W2 + b2 ==========
// One block per 128 rows; h and t resident in LDS (XOR-swizzled).
// W1t/W2t are L2-resident (1 MB total) -> B-fragments read DIRECTLY from
// global (no LDS staging, no per-K barriers). 9 barriers total per block.
__global__ __launch_bounds__(512, 2) void ffn_fused_kernel(
    const float* __restrict__ x, const float* __restrict__ lnw,
    const float* __restrict__ lnb, const bf16* __restrict__ W1t,
    const float* __restrict__ b1, const bf16* __restrict__ W2t,
    const float* __restrict__ b2, float* __restrict__ out)
{
  __shared__ __align__(16) char hbuf[128 * 512];   // bf16 [128][256] swizzled
  __shared__ __align__(16) char tbuf[128 * 512];   // bf16 [128][256] swizzled
  int tid = threadIdx.x;
  int wid = tid >> 6, lane = tid & 63;
  size_t row0 = (size_t)blockIdx.x * 128;

  // ---- LN(x) -> hbuf ----
  {
    float4 wv = ((const float4*)lnw)[lane];
    float4 bv = ((const float4*)lnb)[lane];
    for (int it = 0; it < 16; it++) {
      int row = wid * 16 + it;
      float4 v = ((const float4*)(x + (row0 + row) * 256))[lane];
      float s = v.x+v.y+v.z+v.w, q = v.x*v.x+v.y*v.y+v.z*v.z+v.w*v.w;
      #pragma unroll
      for (int o = 32; o; o >>= 1) { s += __shfl_xor(s, o); q += __shfl_xor(q, o); }
      float mu = s * (1.f/256.f);
      float rs = rsqrtf(q*(1.f/256.f) - mu*mu + LN_EPS);
      bf16x4v o4;
      o4[0] = (bf16)((v.x-mu)*rs*wv.x + bv.x);
      o4[1] = (bf16)((v.y-mu)*rs*wv.y + bv.y);
      o4[2] = (bf16)((v.z-mu)*rs*wv.z + bv.z);
      o4[3] = (bf16)((v.w-mu)*rs*wv.w + bv.w);
      *(bf16x4v*)(hbuf + row*512 + ((lane*8) ^ ((row & 7) << 4))) = o4;
    }
  }
  __syncthreads();

  int wm = (wid >> 2) * 64;        // 0 / 64
  int wn = (wid & 3) * 64;         // 0..192
  int fr = lane & 15;
  int fk = (lane >> 4) * 8;        // element offset in K
  int fk2 = fk * 2;                // byte offset
  int cn0 = lane & 15, rq = (lane >> 4) * 4;
  int arow[4], asw[4], brow[4];
  #pragma unroll
  for (int mi = 0; mi < 4; mi++) {
    arow[mi] = wm + mi*16 + fr;
    asw[mi]  = (arow[mi] & 7) << 4;
  }
  #pragma unroll
  for (int ni = 0; ni < 4; ni++) brow[ni] = wn + ni*16 + fr;

  f32x4 acc2[4][4];
  #pragma unroll
  for (int mi = 0; mi < 4; mi++)
    #pragma unroll
    for (int ni = 0; ni < 4; ni++)
      acc2[mi][ni] = (f32x4){0.f, 0.f, 0.f, 0.f};

  for (int cf = 0; cf < 4; cf++) {
    // ---- GEMM1: acc1 = h @ W1t[cf*256 + n][k], K = 256; B direct from L2 ----
    f32x4 acc1[4][4];
    #pragma unroll
    for (int mi = 0; mi < 4; mi++)
      #pragma unroll
      for (int ni = 0; ni < 4; ni++)
        acc1[mi][ni] = (f32x4){0.f, 0.f, 0.f, 0.f};
    #pragma unroll 2
    for (int k0 = 0; k0 < 256; k0 += 32) {
      bf16x8 af[4], bf_[4];
      #pragma unroll
      for (int ni = 0; ni < 4; ni++)
        bf_[ni] = *(const bf16x8*)&W1t[(size_t)(cf*256 + brow[ni]) * 256 + k0 + fk];
      #pragma unroll
      for (int mi = 0; mi < 4; mi++)
        af[mi] = *(const bf16x8*)(hbuf + arow[mi]*512 + ((k0*2 + fk2) ^ asw[mi]));
      #pragma unroll
      for (int mi = 0; mi < 4; mi++)
        #pragma unroll
        for (int ni = 0; ni < 4; ni++)
          acc1[mi][ni] = __builtin_amdgcn_mfma_f32_16x16x32_bf16(af[mi], bf_[ni], acc1[mi][ni], 0, 0, 0);
    }
    // ---- t = relu(acc1 + b1) -> tbuf ----
    __syncthreads();   // previous chunk's GEMM2 done reading tbuf
    #pragma unroll
    for (int ni = 0; ni < 4; ni++) {
      int col = wn + ni*16 + cn0;
      float bb = b1[cf*256 + col];
      #pragma unroll
      for (int mi = 0; mi < 4; mi++) {
        #pragma unroll
        for (int r = 0; r < 4; r++) {
          int row = wm + mi*16 + rq + r;
          float v = fmaxf(acc1[mi][ni][r] + bb, 0.f);
          *(bf16*)(tbuf + row*512 + ((col*2) ^ ((row & 7) << 4))) = (bf16)v;
        }
      }
    }
    __syncthreads();   // tbuf ready
    // ---- GEMM2: acc2 += t @ W2t[n][cf*256 + k], K = 256; B direct from L2 ----
    #pragma unroll 2
    for (int k0 = 0; k0 < 256; k0 += 32) {
      bf16x8 af[4], bf_[4];
      #pragma unroll
      for (int ni = 0; ni < 4; ni++)
        bf_[ni] = *(const bf16x8*)&W2t[(size_t)brow[ni] * 1024 + cf*256 + k0 + fk];
      #pragma unroll
      for (int mi = 0; mi < 4; mi++)
        af[mi] = *(const bf16x8*)(tbuf + arow[mi]*512 + ((k0*2 + fk2) ^ asw[mi]));
      #pragma unroll
      for (int mi = 0; mi < 4; mi++)
        #pragma unroll
        for (int ni = 0; ni < 4; ni++)
          acc2[mi][ni] = __builtin_amdgcn_mfma_f32_16x16x32_bf16(af[mi], bf_[ni], acc2[mi][ni], 0, 0, 0);
    }
  }
  // ---- epilogue: out = x + acc2 + b2 ----
  #pragma unroll
  for (int ni = 0; ni < 4; ni++) {
    int col = wn + ni*16 + cn0;
    float bb = b2[col];
    #pragma unroll
    for (int mi = 0; mi < 4; mi++) {
      #pragma unroll
      for (int r = 0; r < 4; r++) {
        size_t grow = row0 + wm + mi*16 + rq + r;
        out[grow*256 + col] = x[grow*256 + col] + acc2[mi][ni][r] + bb;
      }
    }
  }
}

extern "C" void kernel_launch(void* const* d_in, const int* in_sizes, int n_in,
                              void* d_out, int out_size, void* d_ws, size_t ws_size,
                              hipStream_t stream)
{
  (void)in_sizes; (void)n_in; (void)out_size; (void)ws_size;
  const float* msa = (const float*)d_in[0];
  const float* rr  = (const float*)d_in[1];
  const float* lmw = (const float*)d_in[2];
  const float* lmb = (const float*)d_in[3];
  const float* lrw = (const float*)d_in[4];
  const float* lrb = (const float*)d_in[5];
  const float* WA  = (const float*)d_in[6];
  // d_in[7] = bA: constant over the softmax (key) axis -> cancels exactly. Unused.
  const float* WV  = (const float*)d_in[8];
  const float* bV  = (const float*)d_in[9];
  const float* WO  = (const float*)d_in[10];
  const float* bO  = (const float*)d_in[11];
  const float* lfw = (const float*)d_in[12];
  const float* lfb = (const float*)d_in[13];
  const float* W1  = (const float*)d_in[14];
  const float* b1  = (const float*)d_in[15];
  const float* W2  = (const float*)d_in[16];
  const float* b2  = (const float*)d_in[17];
  float* out = (float*)d_out;
  char* ws = (char*)d_ws;
  float* S   = (float*)(ws + 0);         // [512][512][4] f32 = 4.2 MB
  bf16* Abuf = (bf16*)(ws + 4194304);    // [4][512][512] bf16 = 2.1 MB
  bf16* m    = (bf16*)(ws + 6291456);    // [32768][256] bf16 = 16.8 MB
  bf16* Vt   = (bf16*)(ws + 23068672);   // [4][4096][512] bf16 = 16.8 MB
  bf16* agg  = (bf16*)(ws + 39845888);   // [32768][256] bf16 = 16.8 MB
  bf16* WVt  = (bf16*)(ws + 83886080);   // transposed bf16 weights
  bf16* WOt  = WVt + 65536;
  bf16* W1t  = WOt + 65536;
  bf16* W2t  = W1t + 262144;

  transpose_all_kernel<<<640, dim3(32, 8), 0, stream>>>(WV, WO, W1, W2, WVt, WOt, W1t, W2t);

  // m = LN(msa) bf16
  ln_rows_kernel<<<8192, 256, 0, stream>>>(msa, lmw, lmb, m);
  // S[i,j,g] logits (symmetric), rr read once
  sym_ln_wa_kernel<<<dim3(528, 4), 256, 0, stream>>>(rr, lrw, lrb, WA, S);
  // Vt[g][d*64+c6][j] = (m @ WV + bV)^T, computed as WVt @ m^T
  gemm_bt_kernel<0><<<dim3(256, 2, 1), 256, 0, stream>>>(WVt, m, Vt, bV, nullptr, 256, 32768, 256);
  // A[g][i][j] softmax
  softmax_kernel<<<128, 256, 0, stream>>>(S, Abuf);
  // agg[(d,i)][g*64+c6] = sum_j A_g[i,j] * Vt_g[dc][j]
  gemm_bt_kernel<1><<<dim3(32, 4, 4), 256, 0, stream>>>(Abuf, Vt, agg, nullptr, nullptr, 512, 4096, 512);
  // x = agg @ WO + bO + msa  -> d_out (f32)
  gemm_bt_kernel<2><<<dim3(2, 256, 1), 256, 0, stream>>>(agg, WOt, out, bO, msa, 32768, 256, 256);
  // out = x + relu(LN(x)@W1+b1)@W2 + b2   (fused FFN, in place on d_out)
  ffn_fused_kernel<<<256, 512, 0, stream>>>(out, lfw, lfb, W1t, b1, W2t, b2, out);
}